// Round 13
// baseline (876.843 us; speedup 1.0000x reference)
//
#include <hip/hip_runtime.h>
#include <math.h>

typedef _Float16 half8 __attribute__((ext_vector_type(8)));
typedef float floatx4 __attribute__((ext_vector_type(4)));
typedef unsigned long long u64;

#define MFMA16(a, b, c) __builtin_amdgcn_mfma_f32_16x16x32_f16((a), (b), (c), 0, 0, 0)
#define AARG __ATOMIC_RELAXED, __HIP_MEMORY_SCOPE_AGENT

static constexpr float C11 = 4.8828125e-4f;  // 2^-11
static constexpr int SLOTS = 257;
static constexpr int LSTRIDE = SLOTS * 8 * 128;

// Deep tagged-atom rings (proven r4-r12) + x split planes.
__device__ u64 g_exch[2 * LSTRIDE];
__device__ _Float16 g_xhi[8388608];
__device__ _Float16 g_xlo[8388608];
__device__ unsigned g_done;  // scan-WG completion counter (ballast exit)

__global__ __launch_bounds__(256) void zero_k() {
  unsigned i = blockIdx.x * 256 + threadIdx.x;  // grid 2056
  if (i < 2 * LSTRIDE) g_exch[i] = 0;
  if (i == 0) g_done = 0;
}

__device__ __forceinline__ u64 ald(const u64* p) { return __hip_atomic_load(p, AARG); }
__device__ __forceinline__ void ast(u64* p, u64 v) { __hip_atomic_store(p, v, AARG); }

// Barrier that does NOT drain vmcnt (r11-verified neutral+correct).
__device__ __forceinline__ void barrier_lds() {
  __builtin_amdgcn_sched_barrier(0);
  asm volatile("s_waitcnt lgkmcnt(0)" ::: "memory");
  __builtin_amdgcn_s_barrier();
  __builtin_amdgcn_sched_barrier(0);
}

// f32 -> normal-f16 hi + 2^11-scaled f16 lo (denorm-proof; verified r2-r12).
__device__ __forceinline__ void split16(float v, _Float16& hi, _Float16& lo) {
  _Float16 h = (fabsf(v) < 6.103515625e-05f) ? (_Float16)0.0f : (_Float16)v;
  hi = h;
  lo = (_Float16)((v - (float)h) * 2048.0f);
}

__global__ __launch_bounds__(256) void presplit_k(const float* __restrict__ x) {
  int i = (blockIdx.x * 256 + threadIdx.x) * 8;
  floatx4 a = *(const floatx4*)(x + i);
  floatx4 b = *(const floatx4*)(x + i + 4);
  half8 hi, lo;
#pragma unroll
  for (int e = 0; e < 4; ++e) { _Float16 p, q; split16(a[e], p, q); hi[e] = p; lo[e] = q; }
#pragma unroll
  for (int e = 0; e < 4; ++e) { _Float16 p, q; split16(b[e], p, q); hi[4 + e] = p; lo[4 + e] = q; }
  *(half8*)(g_xhi + i) = hi;
  *(half8*)(g_xlo + i) = lo;
}

// Fused scan (r9/r11/r12 structure): 128 scan WGs x 512 threads.
// Waves 0-3 = producers (ih GEMM for gate wv: L0 from x planes, L1 from
// LUT-expanded h0 atoms); waves 4-7 = consumers (recurrent+spike; wave4
// polls). gemm0 pre-pass is FOLDED into L0 producers (r13 change).
template <int LAYER>
__device__ void scan_body(_Float16* lut, float* ihb, unsigned* hw, u64* spike,
                          const float* __restrict__ wih,
                          const float* __restrict__ whh,
                          const float* __restrict__ bias,
                          float* __restrict__ dout, int g, int kwg) {
  const int tid = threadIdx.x;
  const int lane = tid & 63;
  const int wv = tid >> 6;
  const bool prod = wv < 4;
  const int gate = wv & 3;
  const int m16 = lane & 15;
  const int l16 = lane >> 4;

  u64* exch0 = g_exch;
  u64* exchMy = g_exch + LAYER * LSTRIDE;

  if (tid < 256) {
#pragma unroll
    for (int e = 0; e < 8; ++e)
      lut[tid * 8 + e] = ((tid >> e) & 1) ? (_Float16)1.0f : (_Float16)0.0f;
  }

  // Weight fragments in VGPRs: producers get W_ih (both layers now),
  // consumers get W_hh.
  half8 FH[2][8], FL[2][8];
  {
    const float* wsrc = prod ? wih : whh;
#pragma unroll
    for (int t2 = 0; t2 < 2; ++t2) {
      int grow = gate * 256 + 32 * kwg + t2 * 16 + m16;
#pragma unroll
      for (int q = 0; q < 8; ++q) {
        const float* src = wsrc + (size_t)grow * 256 + 32 * q + 8 * l16;
        floatx4 v0 = *(const floatx4*)src;
        floatx4 v1 = *(const floatx4*)(src + 4);
        half8 hi, lo;
#pragma unroll
        for (int e = 0; e < 4; ++e) { _Float16 p, q2; split16(v0[e], p, q2); hi[e] = p; lo[e] = q2; }
#pragma unroll
        for (int e = 0; e < 4; ++e) { _Float16 p, q2; split16(v1[e], p, q2); hi[4 + e] = p; lo[4 + e] = q2; }
        FH[t2][q] = hi;
        FL[t2][q] = lo;
      }
    }
  }
  float bl[2];
#pragma unroll
  for (int t2 = 0; t2 < 2; ++t2) bl[t2] = bias[gate * 256 + 32 * kwg + t2 * 16 + m16];

  floatx4 ihA0[2], ihA1[2];  // producer ih regs (written to ihb in part 1)
  half8 xrh[8], xrl[8];      // L0 producer x fragments (consume-then-reissue)
  u64 xwA[8];                // L1 producer in-flight atoms
  unsigned xw[8];
  u64 cst = 0;
  int polls = 0;
  const int POLL_MAX = 1 << 22;  // bail visibly, never hang

  auto issue_x = [&](int ln) {  // L0 producers: x plane fragments
    size_t base = ((size_t)ln * 128 + 16 * g + m16) * 256 + 8 * l16;
#pragma unroll
    for (int q = 0; q < 8; ++q) {
      xrh[q] = *(const half8*)(g_xhi + base + 32 * q);
      xrl[q] = *(const half8*)(g_xlo + base + 32 * q);
    }
  };
  auto ihx_mfma = [&]() {  // L0 producers: ih from x (gemm0_k order parity)
    floatx4 zz = {0.f, 0.f, 0.f, 0.f};
    floatx4 A2[2];
    ihA0[0] = ihA0[1] = zz;
    ihA1[0] = ihA1[1] = zz;
    A2[0] = A2[1] = zz;
#pragma unroll
    for (int q = 0; q < 8; ++q)
#pragma unroll
      for (int t2 = 0; t2 < 2; ++t2) {
        ihA0[t2] = MFMA16(xrh[q], FH[t2][q], ihA0[t2]);
        ihA1[t2] = MFMA16(xrh[q], FL[t2][q], ihA1[t2]);
        ihA1[t2] = MFMA16(xrl[q], FH[t2][q], ihA1[t2]);
        A2[t2] = MFMA16(xrl[q], FL[t2][q], A2[t2]);
      }
    // fold exactly as gemm0_k did: plo = f16(A1 + C11*A2), consumer saw (float)plo
#pragma unroll
    for (int t2 = 0; t2 < 2; ++t2)
#pragma unroll
      for (int r = 0; r < 4; ++r)
        ihA1[t2][r] = (float)(_Float16)(ihA1[t2][r] + C11 * A2[t2][r]);
  };
  auto issue_xw = [&](int tag) {  // L1 producers: fire-and-forget atoms
    const u64* page = exch0 + (size_t)tag * 1024 + g * 128 + m16;
#pragma unroll
    for (int q = 0; q < 8; ++q) xwA[q] = ald(page + q * 16);
  };
  auto consume_xw = [&](int tag) {  // validate; fallback poll if stale
    bool ok = true;
#pragma unroll
    for (int q = 0; q < 8; ++q) ok = ok && ((unsigned)xwA[q] == (unsigned)tag);
    if (!__all(ok)) {
      const u64* page = exch0 + (size_t)tag * 1024 + g * 128 + m16;
      for (;;) {
#pragma unroll
        for (int q = 0; q < 8; ++q) xwA[q] = ald(page + q * 16);
        bool k2 = true;
#pragma unroll
        for (int q = 0; q < 8; ++q) k2 = k2 && ((unsigned)xwA[q] == (unsigned)tag);
        if (__all(k2)) break;
        if (++polls > POLL_MAX) break;
      }
    }
#pragma unroll
    for (int q = 0; q < 8; ++q) xw[q] = (unsigned)(xwA[q] >> 32);
  };
  auto ih_mfma = [&]() {  // L1 producers: ih from LUT-expanded h0
    floatx4 zz = {0.f, 0.f, 0.f, 0.f};
    ihA0[0] = ihA0[1] = zz;
    ihA1[0] = ihA1[1] = zz;
#pragma unroll
    for (int q = 0; q < 8; ++q) {
      unsigned byt = (xw[q] >> (8 * l16)) & 0xFFu;
      half8 ah = *(const half8*)(lut + byt * 8);
#pragma unroll
      for (int t2 = 0; t2 < 2; ++t2) {
        ihA0[t2] = MFMA16(ah, FH[t2][q], ihA0[t2]);
        ihA1[t2] = MFMA16(ah, FL[t2][q], ihA1[t2]);
      }
    }
  };
  auto gather16 = [&](u64 v) -> unsigned {
    unsigned a0 = __shfl((unsigned)v, lane & 3);
    unsigned a1 = __shfl((unsigned)(v >> 32), lane & 3);
    unsigned b0 = __shfl((unsigned)v, 4 + (lane & 3));
    unsigned b1 = __shfl((unsigned)(v >> 32), 4 + (lane & 3));
    u64 A = ((u64)a1 << 32) | a0;
    u64 B = ((u64)b1 << 32) | b0;
    int sh = 16 * ((lane & 15) >> 2);
    return (unsigned)((A >> sh) & 0xFFFFull) |
           ((unsigned)((B >> sh) & 0xFFFFull) << 16);
  };

  // ---- prologue ----
  if (prod) {
    if constexpr (LAYER == 0) {
      issue_x(0);
      ihx_mfma();  // ih(0) -> regs (no lut dependency)
      issue_x(1);
    } else {
      issue_xw(1);
      consume_xw(1);  // genuine wait for L0 step 0
      ih_mfma();      // ih(0) -> regs
      issue_xw(2);
    }
  }
  __syncthreads();  // lut + weights ready (full sync, once, outside the loop)

#pragma unroll 1
  for (int l = 0; l < 256; ++l) {
    // part 1: producers write ihbuf(l) from regs; wave4 polls h(l)
    if (prod) {
#pragma unroll
      for (int t2 = 0; t2 < 2; ++t2) {
        float* b2 = ihb + ((gate * 2 + t2) * 8) * 64 + lane;
#pragma unroll
        for (int r = 0; r < 4; ++r) {
          b2[r * 64] = ihA0[t2][r];
          b2[(4 + r) * 64] = ihA1[t2][r];
        }
      }
    } else if (wv == 4 && l > 0) {
      const u64* pa = exchMy + (size_t)l * 1024 + g * 128 + 2 * lane;
      u64 v0 = ald(pa), v1 = ald(pa + 1);
      for (;;) {
        if (__all(((unsigned)v0 == (unsigned)l) && ((unsigned)v1 == (unsigned)l))) break;
        v0 = ald(pa);
        v1 = ald(pa + 1);
        if (++polls > POLL_MAX) break;
      }
      hw[2 * lane] = (unsigned)(v0 >> 32);
      hw[2 * lane + 1] = (unsigned)(v1 >> 32);
    }
    barrier_lds();  // A: ihbuf(l) + hw(l) ready (LDS-ordered; vmcnt in flight)
    // part 2: producers build ih(l+1); consumers do recurrent + spikes
    if (prod) {
      if (l < 255) {
        if constexpr (LAYER == 0) {
          ihx_mfma();  // consumes x(l+1) regs
          issue_x(l + 2 > 255 ? 255 : l + 2);
        } else {
          consume_xw(l + 2);
          ih_mfma();
          if (l + 3 <= 256) issue_xw(l + 3);
        }
      }
    } else {
      floatx4 C0[2], C1[2];
#pragma unroll
      for (int t2 = 0; t2 < 2; ++t2) {
        const float* b2 = ihb + ((gate * 2 + t2) * 8) * 64 + lane;
#pragma unroll
        for (int r = 0; r < 4; ++r) {
          C0[t2][r] = b2[r * 64];
          C1[t2][r] = b2[(4 + r) * 64];
        }
      }
      if (l > 0) {
#pragma unroll
        for (int q = 0; q < 8; ++q) {
          unsigned mw = hw[q * 16 + m16];
          unsigned byt = (mw >> (8 * l16)) & 0xFFu;
          half8 af = *(const half8*)(lut + byt * 8);
          C0[0] = MFMA16(af, FH[0][q], C0[0]);
          C0[1] = MFMA16(af, FH[1][q], C0[1]);
          C1[0] = MFMA16(af, FL[0][q], C1[0]);
          C1[1] = MFMA16(af, FL[1][q], C1[1]);
        }
      }
      u64 bal[2][4];
#pragma unroll
      for (int r = 0; r < 4; ++r) {
        float p0 = C0[0][r] + bl[0] + C11 * C1[0][r];
        float p1 = C0[1][r] + bl[1] + C11 * C1[1][r];
        bal[0][r] = __ballot(p0 >= 0.0f);
        bal[1][r] = __ballot(p1 >= 0.0f);
      }
      if (lane == 0) {
#pragma unroll
        for (int t2 = 0; t2 < 2; ++t2)
#pragma unroll
          for (int r = 0; r < 4; ++r) spike[gate * 8 + t2 * 4 + r] = bal[t2][r];
      }
    }
    barrier_lds();  // B: spikes ready (LDS-ordered; vmcnt in flight)
    // part 3: bitwise update (all waves) + producer-side outputs
    {
      int idx = lane & 7;
      u64 iS = spike[idx], fS = spike[8 + idx];
      u64 gS = spike[16 + idx];
      cst = (fS & cst) | (iS & gS);  // c = min(f*c+i*g, 1) exactly
    }
    u64 hS = spike[24 + (lane & 7)] & cst;  // h = o*c
    if (wv == 0) {
      unsigned hu = gather16(hS);
      if (lane < 16)
        ast(exchMy + (size_t)(l + 1) * 1024 + g * 128 + kwg * 16 + lane,
            ((u64)hu << 32) | (unsigned)(l + 1));
    }
    if (LAYER == 1 && wv == 1) {
      unsigned hu = gather16(hS);
      if (lane < 16) {
        float* frow = dout + ((size_t)l * 128 + 16 * g + lane) * 256 + 32 * kwg;
#pragma unroll
        for (int c4 = 0; c4 < 8; ++c4) {
          floatx4 v;
#pragma unroll
          for (int j = 0; j < 4; ++j) v[j] = ((hu >> (c4 * 4 + j)) & 1) ? 1.0f : 0.0f;
          *(floatx4*)(frow + c4 * 4) = v;
        }
      }
    }
    if (l == 255 && wv == 2) {
      unsigned hu = gather16(hS);
      unsigned cu = gather16(cst);
      if (lane < 16) {
        float* shp = dout + 8388608 + LAYER * 32768 +
                     (size_t)(16 * g + lane) * 256 + 32 * kwg;
        float* scp = shp + 65536;
#pragma unroll
        for (int c4 = 0; c4 < 8; ++c4) {
          floatx4 vh, vc;
#pragma unroll
          for (int j = 0; j < 4; ++j) {
            vh[j] = ((hu >> (c4 * 4 + j)) & 1) ? 1.0f : 0.0f;
            vc[j] = ((cu >> (c4 * 4 + j)) & 1) ? 1.0f : 0.0f;
          }
          *(floatx4*)(shp + c4 * 4) = vh;
          *(floatx4*)(scp + c4 * 4) = vc;
        }
      }
    }
  }
  // signal completion (ballast WGs exit when all 128 scan WGs are done)
  __syncthreads();
  if (tid == 0)
    __hip_atomic_fetch_add(&g_done, 1u, __ATOMIC_RELAXED, __HIP_MEMORY_SCOPE_AGENT);
}

__global__ __launch_bounds__(512, 2) void spike_scan(
    const float* __restrict__ wih0, const float* __restrict__ wih1,
    const float* __restrict__ whh0, const float* __restrict__ whh1,
    const float* __restrict__ b0, const float* __restrict__ b1,
    float* __restrict__ dout) {
  __shared__ __align__(16) _Float16 lut[256 * 8];
  __shared__ __align__(16) float ihb[4 * 2 * 8 * 64];
  __shared__ unsigned hw[128];
  __shared__ u64 spike[32];

  int bi = blockIdx.x;  // 256 WGs: 128 scan (64/layer) + 128 ballast
  if (bi >= 128) {
    float a0 = (float)threadIdx.x * 0.001f + 1.0f;
    float a1 = a0 + 0.1f, a2 = a0 + 0.2f, a3 = a0 + 0.3f;
    float a4 = a0 + 0.4f, a5 = a0 + 0.5f, a6 = a0 + 0.6f, a7 = a0 + 0.7f;
    half8 hb;
#pragma unroll
    for (int e = 0; e < 8; ++e) hb[e] = (_Float16)0.5f;
    floatx4 acc = {0.f, 0.f, 0.f, 0.f};
#pragma unroll 1
    for (int it = 0; it < 8192; ++it) {
#pragma unroll
      for (int k = 0; k < 64; ++k) {
        a0 = __builtin_fmaf(a0, 1.0000001f, 1e-7f);
        a1 = __builtin_fmaf(a1, 1.0000001f, 1e-7f);
        a2 = __builtin_fmaf(a2, 1.0000001f, 1e-7f);
        a3 = __builtin_fmaf(a3, 1.0000001f, 1e-7f);
        a4 = __builtin_fmaf(a4, 1.0000001f, 1e-7f);
        a5 = __builtin_fmaf(a5, 1.0000001f, 1e-7f);
        a6 = __builtin_fmaf(a6, 1.0000001f, 1e-7f);
        a7 = __builtin_fmaf(a7, 1.0000001f, 1e-7f);
      }
      acc = MFMA16(hb, hb, acc);
      if (__hip_atomic_load(&g_done, __ATOMIC_RELAXED, __HIP_MEMORY_SCOPE_AGENT) >= 128u)
        break;
    }
    asm volatile("" ::"v"(a0), "v"(a1), "v"(a2), "v"(a3), "v"(a4), "v"(a5),
                 "v"(a6), "v"(a7), "v"(acc[0]));  // keep live (rule #17)
    return;
  }
  int g = bi & 7;
  int kwg = (bi >> 3) & 7;
  if ((bi >> 6) == 0)
    scan_body<0>(lut, ihb, hw, spike, wih0, whh0, b0, dout, g, kwg);
  else
    scan_body<1>(lut, ihb, hw, spike, wih1, whh1, b1, dout, g, kwg);
}

extern "C" void kernel_launch(void* const* d_in, const int* in_sizes, int n_in,
                              void* d_out, int out_size, void* d_ws, size_t ws_size,
                              hipStream_t stream) {
  (void)in_sizes; (void)n_in; (void)out_size; (void)d_ws; (void)ws_size;
  const float* x = (const float*)d_in[0];
  const float* wih0 = (const float*)d_in[1];
  const float* whh0 = (const float*)d_in[2];
  const float* b0 = (const float*)d_in[3];
  const float* wih1 = (const float*)d_in[4];
  const float* whh1 = (const float*)d_in[5];
  const float* b1 = (const float*)d_in[6];
  float* dout = (float*)d_out;

  zero_k<<<2056, 256, 0, stream>>>();
  presplit_k<<<4096, 256, 0, stream>>>(x);
  spike_scan<<<256, 512, 0, stream>>>(wih0, wih1, whh0, whh1, b0, b1, dout);
}

// Round 14
// 791.422 us; speedup vs baseline: 1.1079x; 1.1079x over previous
//
#include <hip/hip_runtime.h>
#include <math.h>

typedef _Float16 half8 __attribute__((ext_vector_type(8)));
typedef _Float16 half4v __attribute__((ext_vector_type(4)));
typedef float floatx4 __attribute__((ext_vector_type(4)));
typedef unsigned long long u64;

#define MFMA16(a, b, c) __builtin_amdgcn_mfma_f32_16x16x32_f16((a), (b), (c), 0, 0, 0)
#define AARG __ATOMIC_RELAXED, __HIP_MEMORY_SCOPE_AGENT

static constexpr float C11 = 4.8828125e-4f;  // 2^-11
static constexpr int SLOTS = 257;
static constexpr int LSTRIDE = SLOTS * 8 * 128;

// Deep tagged-atom rings (proven r4-r12) + x split planes + L0-IH planes.
__device__ u64 g_exch[2 * LSTRIDE];
__device__ _Float16 g_xhi[8388608];
__device__ _Float16 g_xlo[8388608];
__device__ float g_phi[33554432];     // [l][g][kwg][gate][t2][lane][r] f32 = A0
__device__ _Float16 g_plo[33554432];  // same index, f16 = A1 + C11*A2

__global__ __launch_bounds__(256) void zero_k() {
  unsigned i = blockIdx.x * 256 + threadIdx.x;  // grid 2056
  if (i < 2 * LSTRIDE) g_exch[i] = 0;
}

__device__ __forceinline__ u64 ald(const u64* p) { return __hip_atomic_load(p, AARG); }
__device__ __forceinline__ void ast(u64* p, u64 v) { __hip_atomic_store(p, v, AARG); }

// Barrier that does NOT drain vmcnt (r11-verified neutral+correct).
__device__ __forceinline__ void barrier_lds() {
  __builtin_amdgcn_sched_barrier(0);
  asm volatile("s_waitcnt lgkmcnt(0)" ::: "memory");
  __builtin_amdgcn_s_barrier();
  __builtin_amdgcn_sched_barrier(0);
}

// f32 -> normal-f16 hi + 2^11-scaled f16 lo (denorm-proof; verified r2-r12).
__device__ __forceinline__ void split16(float v, _Float16& hi, _Float16& lo) {
  _Float16 h = (fabsf(v) < 6.103515625e-05f) ? (_Float16)0.0f : (_Float16)v;
  hi = h;
  lo = (_Float16)((v - (float)h) * 2048.0f);
}

__global__ __launch_bounds__(256) void presplit_k(const float* __restrict__ x) {
  int i = (blockIdx.x * 256 + threadIdx.x) * 8;
  floatx4 a = *(const floatx4*)(x + i);
  floatx4 b = *(const floatx4*)(x + i + 4);
  half8 hi, lo;
#pragma unroll
  for (int e = 0; e < 4; ++e) { _Float16 p, q; split16(a[e], p, q); hi[e] = p; lo[e] = q; }
#pragma unroll
  for (int e = 0; e < 4; ++e) { _Float16 p, q; split16(b[e], p, q); hi[4 + e] = p; lo[4 + e] = q; }
  *(half8*)(g_xhi + i) = hi;
  *(half8*)(g_xlo + i) = lo;
}

// GEMM0: layer-0 IH planes in fragment layout. 512 WGs x 32 steps (parallel).
__global__ __launch_bounds__(256) void gemm0_k(const float* __restrict__ wih) {
  const int tid = threadIdx.x, lane = tid & 63, wv = tid >> 6;
  const int m16 = lane & 15, l16 = lane >> 4;
  const int bi = blockIdx.x;
  const int lc = bi >> 6, g = (bi >> 3) & 7, kwg = bi & 7;

  half8 WH[2][8], WL[2][8];  // W_ih fragments (gate wv) in VGPRs
#pragma unroll
  for (int t2 = 0; t2 < 2; ++t2) {
    int grow = wv * 256 + 32 * kwg + t2 * 16 + m16;
#pragma unroll
    for (int q = 0; q < 8; ++q) {
      const float* src = wih + (size_t)grow * 256 + 32 * q + 8 * l16;
      floatx4 v0 = *(const floatx4*)src;
      floatx4 v1 = *(const floatx4*)(src + 4);
      half8 hi, lo;
#pragma unroll
      for (int e = 0; e < 4; ++e) { _Float16 p, q2; split16(v0[e], p, q2); hi[e] = p; lo[e] = q2; }
#pragma unroll
      for (int e = 0; e < 4; ++e) { _Float16 p, q2; split16(v1[e], p, q2); hi[4 + e] = p; lo[4 + e] = q2; }
      WH[t2][q] = hi;
      WL[t2][q] = lo;
    }
  }
#pragma unroll 1
  for (int l = lc * 32; l < lc * 32 + 32; ++l) {
    size_t base = ((size_t)l * 128 + 16 * g + m16) * 256 + 8 * l16;
    half8 xh[8], xl[8];
#pragma unroll
    for (int q = 0; q < 8; ++q) {
      xh[q] = *(const half8*)(g_xhi + base + 32 * q);
      xl[q] = *(const half8*)(g_xlo + base + 32 * q);
    }
    floatx4 zz = {0.f, 0.f, 0.f, 0.f};
    floatx4 A0[2], A1[2], A2[2];
    A0[0] = A0[1] = zz; A1[0] = A1[1] = zz; A2[0] = A2[1] = zz;
#pragma unroll
    for (int q = 0; q < 8; ++q)
#pragma unroll
      for (int t2 = 0; t2 < 2; ++t2) {
        A0[t2] = MFMA16(xh[q], WH[t2][q], A0[t2]);  // exact order parity with
        A1[t2] = MFMA16(xh[q], WL[t2][q], A1[t2]);  // the r2-r12 ih_compute
        A1[t2] = MFMA16(xl[q], WH[t2][q], A1[t2]);
        A2[t2] = MFMA16(xl[q], WL[t2][q], A2[t2]);
      }
#pragma unroll
    for (int t2 = 0; t2 < 2; ++t2) {
      size_t off = ((((((size_t)l * 8 + g) * 8 + kwg) * 4 + wv) * 2 + t2) * 64 + lane) * 4;
      *(floatx4*)(g_phi + off) = A0[t2];
      half4v hv;
#pragma unroll
      for (int r = 0; r < 4; ++r) hv[r] = (_Float16)(A1[t2][r] + C11 * A2[t2][r]);
      *(half4v*)(g_plo + off) = hv;
    }
  }
}

// Fused scan (r9/r11/r12 structure): 128 scan WGs x 512 threads.
// Waves 0-3 = producers (ih for gate wv), waves 4-7 = consumers
// (recurrent+spike; wave4 polls). r14 change: wave4's poll is a 4-deep
// rotating probe pipeline (counted vmcnt waits -> detection ~ visibility+RT
// instead of +1.5RT). No ballast (r11/r12 A/B: ballast hurt the scan).
template <int LAYER>
__device__ void scan_body(_Float16* lut, float* ihb, unsigned* hw, u64* spike,
                          const float* __restrict__ wih,
                          const float* __restrict__ whh,
                          const float* __restrict__ bias,
                          float* __restrict__ dout, int g, int kwg) {
  const int tid = threadIdx.x;
  const int lane = tid & 63;
  const int wv = tid >> 6;
  const bool prod = wv < 4;
  const int gate = wv & 3;
  const int m16 = lane & 15;
  const int l16 = lane >> 4;

  u64* exch0 = g_exch;
  u64* exchMy = g_exch + LAYER * LSTRIDE;

  if (tid < 256) {
#pragma unroll
    for (int e = 0; e < 8; ++e)
      lut[tid * 8 + e] = ((tid >> e) & 1) ? (_Float16)1.0f : (_Float16)0.0f;
  }

  // Weight fragments in VGPRs: consumers get W_hh; L1 producers get W_ih1.
  half8 FH[2][8], FL[2][8];
  if (!prod || LAYER == 1) {
    const float* wsrc = prod ? wih : whh;
#pragma unroll
    for (int t2 = 0; t2 < 2; ++t2) {
      int grow = gate * 256 + 32 * kwg + t2 * 16 + m16;
#pragma unroll
      for (int q = 0; q < 8; ++q) {
        const float* src = wsrc + (size_t)grow * 256 + 32 * q + 8 * l16;
        floatx4 v0 = *(const floatx4*)src;
        floatx4 v1 = *(const floatx4*)(src + 4);
        half8 hi, lo;
#pragma unroll
        for (int e = 0; e < 4; ++e) { _Float16 p, q2; split16(v0[e], p, q2); hi[e] = p; lo[e] = q2; }
#pragma unroll
        for (int e = 0; e < 4; ++e) { _Float16 p, q2; split16(v1[e], p, q2); hi[4 + e] = p; lo[4 + e] = q2; }
        FH[t2][q] = hi;
        FL[t2][q] = lo;
      }
    }
  }
  float bl[2];
#pragma unroll
  for (int t2 = 0; t2 < 2; ++t2) bl[t2] = bias[gate * 256 + 32 * kwg + t2 * 16 + m16];

  floatx4 ihA0[2], ihA1[2];  // L1 producer ih regs
  floatx4 phv[2];            // L0 producer plane regs
  half4v plv[2];
  u64 xwA[8];
  unsigned xw[8];
  u64 cst = 0;
  int polls = 0;
  const int POLL_MAX = 1 << 22;  // bail visibly, never hang

  auto issue_pl = [&](int l) {  // L0 producers
#pragma unroll
    for (int t2 = 0; t2 < 2; ++t2) {
      size_t off = ((((((size_t)l * 8 + g) * 8 + kwg) * 4 + gate) * 2 + t2) * 64 + lane) * 4;
      phv[t2] = *(const floatx4*)(g_phi + off);
      plv[t2] = *(const half4v*)(g_plo + off);
    }
  };
  auto issue_xw = [&](int tag) {  // L1 producers: fire-and-forget atoms
    const u64* page = exch0 + (size_t)tag * 1024 + g * 128 + m16;
#pragma unroll
    for (int q = 0; q < 8; ++q) xwA[q] = ald(page + q * 16);
  };
  auto consume_xw = [&](int tag) {  // validate; fallback poll if stale
    bool ok = true;
#pragma unroll
    for (int q = 0; q < 8; ++q) ok = ok && ((unsigned)xwA[q] == (unsigned)tag);
    if (!__all(ok)) {
      const u64* page = exch0 + (size_t)tag * 1024 + g * 128 + m16;
      for (;;) {
#pragma unroll
        for (int q = 0; q < 8; ++q) xwA[q] = ald(page + q * 16);
        bool k2 = true;
#pragma unroll
        for (int q = 0; q < 8; ++q) k2 = k2 && ((unsigned)xwA[q] == (unsigned)tag);
        if (__all(k2)) break;
        if (++polls > POLL_MAX) break;
      }
    }
#pragma unroll
    for (int q = 0; q < 8; ++q) xw[q] = (unsigned)(xwA[q] >> 32);
  };
  auto ih_mfma = [&]() {  // L1 producers: ih from LUT-expanded h0
    floatx4 zz = {0.f, 0.f, 0.f, 0.f};
    ihA0[0] = ihA0[1] = zz;
    ihA1[0] = ihA1[1] = zz;
#pragma unroll
    for (int q = 0; q < 8; ++q) {
      unsigned byt = (xw[q] >> (8 * l16)) & 0xFFu;
      half8 ah = *(const half8*)(lut + byt * 8);
#pragma unroll
      for (int t2 = 0; t2 < 2; ++t2) {
        ihA0[t2] = MFMA16(ah, FH[t2][q], ihA0[t2]);
        ihA1[t2] = MFMA16(ah, FL[t2][q], ihA1[t2]);
      }
    }
  };
  auto gather16 = [&](u64 v) -> unsigned {
    unsigned a0 = __shfl((unsigned)v, lane & 3);
    unsigned a1 = __shfl((unsigned)(v >> 32), lane & 3);
    unsigned b0 = __shfl((unsigned)v, 4 + (lane & 3));
    unsigned b1 = __shfl((unsigned)(v >> 32), 4 + (lane & 3));
    u64 A = ((u64)a1 << 32) | a0;
    u64 B = ((u64)b1 << 32) | b0;
    int sh = 16 * ((lane & 15) >> 2);
    return (unsigned)((A >> sh) & 0xFFFFull) |
           ((unsigned)((B >> sh) & 0xFFFFull) << 16);
  };

  // ---- prologue ----
  if (prod) {
    if constexpr (LAYER == 0) {
      issue_pl(0);
    } else {
      issue_xw(1);
      consume_xw(1);  // genuine wait for L0 step 0
      ih_mfma();      // ih(0) -> regs
      issue_xw(2);
    }
  }
  __syncthreads();  // lut + weights ready (full sync, once, outside the loop)

#pragma unroll 1
  for (int l = 0; l < 256; ++l) {
    // part 1: producers write ihbuf(l); wave4 polls h(l) (4-deep pipeline)
    if (prod) {
#pragma unroll
      for (int t2 = 0; t2 < 2; ++t2) {
        float* b2 = ihb + ((gate * 2 + t2) * 8) * 64 + lane;
        if constexpr (LAYER == 0) {
#pragma unroll
          for (int r = 0; r < 4; ++r) {
            b2[r * 64] = phv[t2][r];
            b2[(4 + r) * 64] = (float)plv[t2][r];
          }
        } else {
#pragma unroll
          for (int r = 0; r < 4; ++r) {
            b2[r * 64] = ihA0[t2][r];
            b2[(4 + r) * 64] = ihA1[t2][r];
          }
        }
      }
    } else if (wv == 4 && l > 0) {
      const u64* pa = exchMy + (size_t)l * 1024 + g * 128 + 2 * lane;
      unsigned tg = (unsigned)l;
      // 4-deep rotating probe pipeline: check the oldest pair while three
      // younger probes are in flight (compiler emits counted vmcnt waits).
      u64 p0a = ald(pa), p0b = ald(pa + 1);
      u64 p1a = ald(pa), p1b = ald(pa + 1);
      u64 p2a = ald(pa), p2b = ald(pa + 1);
      u64 p3a = ald(pa), p3b = ald(pa + 1);
      for (;;) {
        if (__all(((unsigned)p0a == tg) && ((unsigned)p0b == tg))) break;
        p0a = p1a; p0b = p1b;
        p1a = p2a; p1b = p2b;
        p2a = p3a; p2b = p3b;
        p3a = ald(pa); p3b = ald(pa + 1);
        if (++polls > POLL_MAX) break;
      }
      hw[2 * lane] = (unsigned)(p0a >> 32);
      hw[2 * lane + 1] = (unsigned)(p0b >> 32);
    }
    barrier_lds();  // A: ihbuf(l) + hw(l) ready (LDS-ordered; vmcnt in flight)
    // part 2: producers build ih(l+1); consumers do recurrent + spikes
    if (prod) {
      if (l < 255) {
        if constexpr (LAYER == 0) {
          issue_pl(l + 1);
        } else {
          consume_xw(l + 2);
          ih_mfma();
          if (l + 3 <= 256) issue_xw(l + 3);
        }
      }
    } else {
      floatx4 C0[2], C1[2];
#pragma unroll
      for (int t2 = 0; t2 < 2; ++t2) {
        const float* b2 = ihb + ((gate * 2 + t2) * 8) * 64 + lane;
#pragma unroll
        for (int r = 0; r < 4; ++r) {
          C0[t2][r] = b2[r * 64];
          C1[t2][r] = b2[(4 + r) * 64];
        }
      }
      if (l > 0) {
#pragma unroll
        for (int q = 0; q < 8; ++q) {
          unsigned mw = hw[q * 16 + m16];
          unsigned byt = (mw >> (8 * l16)) & 0xFFu;
          half8 af = *(const half8*)(lut + byt * 8);
          C0[0] = MFMA16(af, FH[0][q], C0[0]);
          C0[1] = MFMA16(af, FH[1][q], C0[1]);
          C1[0] = MFMA16(af, FL[0][q], C1[0]);
          C1[1] = MFMA16(af, FL[1][q], C1[1]);
        }
      }
      u64 bal[2][4];
#pragma unroll
      for (int r = 0; r < 4; ++r) {
        float p0 = C0[0][r] + bl[0] + C11 * C1[0][r];
        float p1 = C0[1][r] + bl[1] + C11 * C1[1][r];
        bal[0][r] = __ballot(p0 >= 0.0f);
        bal[1][r] = __ballot(p1 >= 0.0f);
      }
      if (lane == 0) {
#pragma unroll
        for (int t2 = 0; t2 < 2; ++t2)
#pragma unroll
          for (int r = 0; r < 4; ++r) spike[gate * 8 + t2 * 4 + r] = bal[t2][r];
      }
    }
    barrier_lds();  // B: spikes ready (LDS-ordered; vmcnt in flight)
    // part 3: bitwise update (all waves) + producer-side outputs
    {
      int idx = lane & 7;
      u64 iS = spike[idx], fS = spike[8 + idx];
      u64 gS = spike[16 + idx];
      cst = (fS & cst) | (iS & gS);  // c = min(f*c+i*g, 1) exactly
    }
    u64 hS = spike[24 + (lane & 7)] & cst;  // h = o*c
    if (wv == 0) {
      unsigned hu = gather16(hS);
      if (lane < 16)
        ast(exchMy + (size_t)(l + 1) * 1024 + g * 128 + kwg * 16 + lane,
            ((u64)hu << 32) | (unsigned)(l + 1));
    }
    if (LAYER == 1 && wv == 1) {
      unsigned hu = gather16(hS);
      if (lane < 16) {
        float* frow = dout + ((size_t)l * 128 + 16 * g + lane) * 256 + 32 * kwg;
#pragma unroll
        for (int c4 = 0; c4 < 8; ++c4) {
          floatx4 v;
#pragma unroll
          for (int j = 0; j < 4; ++j) v[j] = ((hu >> (c4 * 4 + j)) & 1) ? 1.0f : 0.0f;
          *(floatx4*)(frow + c4 * 4) = v;
        }
      }
    }
    if (l == 255 && wv == 2) {
      unsigned hu = gather16(hS);
      unsigned cu = gather16(cst);
      if (lane < 16) {
        float* shp = dout + 8388608 + LAYER * 32768 +
                     (size_t)(16 * g + lane) * 256 + 32 * kwg;
        float* scp = shp + 65536;
#pragma unroll
        for (int c4 = 0; c4 < 8; ++c4) {
          floatx4 vh, vc;
#pragma unroll
          for (int j = 0; j < 4; ++j) {
            vh[j] = ((hu >> (c4 * 4 + j)) & 1) ? 1.0f : 0.0f;
            vc[j] = ((cu >> (c4 * 4 + j)) & 1) ? 1.0f : 0.0f;
          }
          *(floatx4*)(shp + c4 * 4) = vh;
          *(floatx4*)(scp + c4 * 4) = vc;
        }
      }
    }
  }
}

__global__ __launch_bounds__(512, 2) void spike_scan(
    const float* __restrict__ wih1, const float* __restrict__ whh0,
    const float* __restrict__ whh1, const float* __restrict__ b0,
    const float* __restrict__ b1, float* __restrict__ dout) {
  __shared__ __align__(16) _Float16 lut[256 * 8];
  __shared__ __align__(16) float ihb[4 * 2 * 8 * 64];
  __shared__ unsigned hw[128];
  __shared__ u64 spike[32];

  int bi = blockIdx.x;  // 128 WGs: 64 per layer (no ballast — r11/r12 A/B)
  int g = bi & 7;
  int kwg = (bi >> 3) & 7;
  if ((bi >> 6) == 0)
    scan_body<0>(lut, ihb, hw, spike, (const float*)nullptr, whh0, b0, dout, g, kwg);
  else
    scan_body<1>(lut, ihb, hw, spike, wih1, whh1, b1, dout, g, kwg);
}

extern "C" void kernel_launch(void* const* d_in, const int* in_sizes, int n_in,
                              void* d_out, int out_size, void* d_ws, size_t ws_size,
                              hipStream_t stream) {
  (void)in_sizes; (void)n_in; (void)out_size; (void)d_ws; (void)ws_size;
  const float* x = (const float*)d_in[0];
  const float* wih0 = (const float*)d_in[1];
  const float* whh0 = (const float*)d_in[2];
  const float* b0 = (const float*)d_in[3];
  const float* wih1 = (const float*)d_in[4];
  const float* whh1 = (const float*)d_in[5];
  const float* b1 = (const float*)d_in[6];
  float* dout = (float*)d_out;

  zero_k<<<2056, 256, 0, stream>>>();
  presplit_k<<<4096, 256, 0, stream>>>(x);
  gemm0_k<<<512, 256, 0, stream>>>(wih0);
  spike_scan<<<128, 512, 0, stream>>>(wih1, whh0, whh1, b0, b1, dout);
}

// Round 15
// 623.970 us; speedup vs baseline: 1.4053x; 1.2684x over previous
//
#include <hip/hip_runtime.h>
#include <math.h>

typedef _Float16 half8 __attribute__((ext_vector_type(8)));
typedef _Float16 half4v __attribute__((ext_vector_type(4)));
typedef float floatx4 __attribute__((ext_vector_type(4)));
typedef unsigned long long u64;

#define MFMA16(a, b, c) __builtin_amdgcn_mfma_f32_16x16x32_f16((a), (b), (c), 0, 0, 0)
#define AARG __ATOMIC_RELAXED, __HIP_MEMORY_SCOPE_AGENT

static constexpr float C11 = 4.8828125e-4f;  // 2^-11
static constexpr int SLOTS = 257;
static constexpr int LSTRIDE = SLOTS * 8 * 128;

// Deep tagged-atom rings (proven r4-r14) + x split planes + L0-IH planes.
__device__ u64 g_exch[2 * LSTRIDE];
__device__ _Float16 g_xhi[8388608];
__device__ _Float16 g_xlo[8388608];
__device__ float g_phi[33554432];     // [l][g][kwg][gate][t2][lane][r] f32 = A0
__device__ _Float16 g_plo[33554432];  // same index, f16 = A1 + C11*A2

__device__ __forceinline__ u64 ald(const u64* p) { return __hip_atomic_load(p, AARG); }
__device__ __forceinline__ void ast(u64* p, u64 v) { __hip_atomic_store(p, v, AARG); }

// Barrier that does NOT drain vmcnt (r11-verified neutral+correct).
__device__ __forceinline__ void barrier_lds() {
  __builtin_amdgcn_sched_barrier(0);
  asm volatile("s_waitcnt lgkmcnt(0)" ::: "memory");
  __builtin_amdgcn_s_barrier();
  __builtin_amdgcn_sched_barrier(0);
}

// f32 -> normal-f16 hi + 2^11-scaled f16 lo (denorm-proof; verified r2-r14).
__device__ __forceinline__ void split16(float v, _Float16& hi, _Float16& lo) {
  _Float16 h = (fabsf(v) < 6.103515625e-05f) ? (_Float16)0.0f : (_Float16)v;
  hi = h;
  lo = (_Float16)((v - (float)h) * 2048.0f);
}

// presplit + ring-zero fused (r15: one fewer launch).
__global__ __launch_bounds__(256) void presplit_k(const float* __restrict__ x) {
  unsigned gi = blockIdx.x * 256 + threadIdx.x;  // grid 4096 -> 1,048,576 thr
  if (gi < 2 * LSTRIDE) g_exch[gi] = 0;
  int i = (int)gi * 8;
  floatx4 a = *(const floatx4*)(x + i);
  floatx4 b = *(const floatx4*)(x + i + 4);
  half8 hi, lo;
#pragma unroll
  for (int e = 0; e < 4; ++e) { _Float16 p, q; split16(a[e], p, q); hi[e] = p; lo[e] = q; }
#pragma unroll
  for (int e = 0; e < 4; ++e) { _Float16 p, q; split16(b[e], p, q); hi[4 + e] = p; lo[4 + e] = q; }
  *(half8*)(g_xhi + i) = hi;
  *(half8*)(g_xlo + i) = lo;
}

// GEMM0: layer-0 IH planes in fragment layout. 512 WGs x 32 steps (parallel).
__global__ __launch_bounds__(256) void gemm0_k(const float* __restrict__ wih) {
  const int tid = threadIdx.x, lane = tid & 63, wv = tid >> 6;
  const int m16 = lane & 15, l16 = lane >> 4;
  const int bi = blockIdx.x;
  const int lc = bi >> 6, g = (bi >> 3) & 7, kwg = bi & 7;

  half8 WH[2][8], WL[2][8];  // W_ih fragments (gate wv) in VGPRs
#pragma unroll
  for (int t2 = 0; t2 < 2; ++t2) {
    int grow = wv * 256 + 32 * kwg + t2 * 16 + m16;
#pragma unroll
    for (int q = 0; q < 8; ++q) {
      const float* src = wih + (size_t)grow * 256 + 32 * q + 8 * l16;
      floatx4 v0 = *(const floatx4*)src;
      floatx4 v1 = *(const floatx4*)(src + 4);
      half8 hi, lo;
#pragma unroll
      for (int e = 0; e < 4; ++e) { _Float16 p, q2; split16(v0[e], p, q2); hi[e] = p; lo[e] = q2; }
#pragma unroll
      for (int e = 0; e < 4; ++e) { _Float16 p, q2; split16(v1[e], p, q2); hi[4 + e] = p; lo[4 + e] = q2; }
      WH[t2][q] = hi;
      WL[t2][q] = lo;
    }
  }
#pragma unroll 1
  for (int l = lc * 32; l < lc * 32 + 32; ++l) {
    size_t base = ((size_t)l * 128 + 16 * g + m16) * 256 + 8 * l16;
    half8 xh[8], xl[8];
#pragma unroll
    for (int q = 0; q < 8; ++q) {
      xh[q] = *(const half8*)(g_xhi + base + 32 * q);
      xl[q] = *(const half8*)(g_xlo + base + 32 * q);
    }
    floatx4 zz = {0.f, 0.f, 0.f, 0.f};
    floatx4 A0[2], A1[2], A2[2];
    A0[0] = A0[1] = zz; A1[0] = A1[1] = zz; A2[0] = A2[1] = zz;
#pragma unroll
    for (int q = 0; q < 8; ++q)
#pragma unroll
      for (int t2 = 0; t2 < 2; ++t2) {
        A0[t2] = MFMA16(xh[q], WH[t2][q], A0[t2]);  // exact order parity with
        A1[t2] = MFMA16(xh[q], WL[t2][q], A1[t2]);  // the r2-r14 ih_compute
        A1[t2] = MFMA16(xl[q], WH[t2][q], A1[t2]);
        A2[t2] = MFMA16(xl[q], WL[t2][q], A2[t2]);
      }
#pragma unroll
    for (int t2 = 0; t2 < 2; ++t2) {
      size_t off = ((((((size_t)l * 8 + g) * 8 + kwg) * 4 + wv) * 2 + t2) * 64 + lane) * 4;
      *(floatx4*)(g_phi + off) = A0[t2];
      half4v hv;
#pragma unroll
      for (int r = 0; r < 4; ++r) hv[r] = (_Float16)(A1[t2][r] + C11 * A2[t2][r]);
      *(half4v*)(g_plo + off) = hv;
    }
  }
}

// Fused scan (r11 structure, verbatim — best measured): 128 WGs x 512 thr.
// Waves 0-3 = producers (ih for gate wv), waves 4-7 = consumers
// (recurrent+spike; wave4 simple-polls). No ballast.
template <int LAYER>
__device__ void scan_body(_Float16* lut, float* ihb, unsigned* hw, u64* spike,
                          const float* __restrict__ wih,
                          const float* __restrict__ whh,
                          const float* __restrict__ bias,
                          float* __restrict__ dout, int g, int kwg) {
  const int tid = threadIdx.x;
  const int lane = tid & 63;
  const int wv = tid >> 6;
  const bool prod = wv < 4;
  const int gate = wv & 3;
  const int m16 = lane & 15;
  const int l16 = lane >> 4;

  u64* exch0 = g_exch;
  u64* exchMy = g_exch + LAYER * LSTRIDE;

  if (tid < 256) {
#pragma unroll
    for (int e = 0; e < 8; ++e)
      lut[tid * 8 + e] = ((tid >> e) & 1) ? (_Float16)1.0f : (_Float16)0.0f;
  }

  // Weight fragments in VGPRs: consumers get W_hh; L1 producers get W_ih1.
  half8 FH[2][8], FL[2][8];
  if (!prod || LAYER == 1) {
    const float* wsrc = prod ? wih : whh;
#pragma unroll
    for (int t2 = 0; t2 < 2; ++t2) {
      int grow = gate * 256 + 32 * kwg + t2 * 16 + m16;
#pragma unroll
      for (int q = 0; q < 8; ++q) {
        const float* src = wsrc + (size_t)grow * 256 + 32 * q + 8 * l16;
        floatx4 v0 = *(const floatx4*)src;
        floatx4 v1 = *(const floatx4*)(src + 4);
        half8 hi, lo;
#pragma unroll
        for (int e = 0; e < 4; ++e) { _Float16 p, q2; split16(v0[e], p, q2); hi[e] = p; lo[e] = q2; }
#pragma unroll
        for (int e = 0; e < 4; ++e) { _Float16 p, q2; split16(v1[e], p, q2); hi[4 + e] = p; lo[4 + e] = q2; }
        FH[t2][q] = hi;
        FL[t2][q] = lo;
      }
    }
  }
  float bl[2];
#pragma unroll
  for (int t2 = 0; t2 < 2; ++t2) bl[t2] = bias[gate * 256 + 32 * kwg + t2 * 16 + m16];

  floatx4 ihA0[2], ihA1[2];  // L1 producer ih regs
  floatx4 phv[2];            // L0 producer plane regs
  half4v plv[2];
  u64 xwA[8];
  unsigned xw[8];
  u64 cst = 0;
  int polls = 0;
  const int POLL_MAX = 1 << 22;  // bail visibly, never hang

  auto issue_pl = [&](int l) {  // L0 producers
#pragma unroll
    for (int t2 = 0; t2 < 2; ++t2) {
      size_t off = ((((((size_t)l * 8 + g) * 8 + kwg) * 4 + gate) * 2 + t2) * 64 + lane) * 4;
      phv[t2] = *(const floatx4*)(g_phi + off);
      plv[t2] = *(const half4v*)(g_plo + off);
    }
  };
  auto issue_xw = [&](int tag) {  // L1 producers: fire-and-forget atoms
    const u64* page = exch0 + (size_t)tag * 1024 + g * 128 + m16;
#pragma unroll
    for (int q = 0; q < 8; ++q) xwA[q] = ald(page + q * 16);
  };
  auto consume_xw = [&](int tag) {  // validate; fallback poll if stale
    bool ok = true;
#pragma unroll
    for (int q = 0; q < 8; ++q) ok = ok && ((unsigned)xwA[q] == (unsigned)tag);
    if (!__all(ok)) {
      const u64* page = exch0 + (size_t)tag * 1024 + g * 128 + m16;
      for (;;) {
#pragma unroll
        for (int q = 0; q < 8; ++q) xwA[q] = ald(page + q * 16);
        bool k2 = true;
#pragma unroll
        for (int q = 0; q < 8; ++q) k2 = k2 && ((unsigned)xwA[q] == (unsigned)tag);
        if (__all(k2)) break;
        if (++polls > POLL_MAX) break;
      }
    }
#pragma unroll
    for (int q = 0; q < 8; ++q) xw[q] = (unsigned)(xwA[q] >> 32);
  };
  auto ih_mfma = [&]() {  // L1 producers: ih from LUT-expanded h0
    floatx4 zz = {0.f, 0.f, 0.f, 0.f};
    ihA0[0] = ihA0[1] = zz;
    ihA1[0] = ihA1[1] = zz;
#pragma unroll
    for (int q = 0; q < 8; ++q) {
      unsigned byt = (xw[q] >> (8 * l16)) & 0xFFu;
      half8 ah = *(const half8*)(lut + byt * 8);
#pragma unroll
      for (int t2 = 0; t2 < 2; ++t2) {
        ihA0[t2] = MFMA16(ah, FH[t2][q], ihA0[t2]);
        ihA1[t2] = MFMA16(ah, FL[t2][q], ihA1[t2]);
      }
    }
  };
  auto gather16 = [&](u64 v) -> unsigned {
    unsigned a0 = __shfl((unsigned)v, lane & 3);
    unsigned a1 = __shfl((unsigned)(v >> 32), lane & 3);
    unsigned b0 = __shfl((unsigned)v, 4 + (lane & 3));
    unsigned b1 = __shfl((unsigned)(v >> 32), 4 + (lane & 3));
    u64 A = ((u64)a1 << 32) | a0;
    u64 B = ((u64)b1 << 32) | b0;
    int sh = 16 * ((lane & 15) >> 2);
    return (unsigned)((A >> sh) & 0xFFFFull) |
           ((unsigned)((B >> sh) & 0xFFFFull) << 16);
  };

  // ---- prologue ----
  if (prod) {
    if constexpr (LAYER == 0) {
      issue_pl(0);
    } else {
      issue_xw(1);
      consume_xw(1);  // genuine wait for L0 step 0
      ih_mfma();      // ih(0) -> regs
      issue_xw(2);
    }
  }
  __syncthreads();  // lut + weights ready (full sync, once, outside the loop)

#pragma unroll 1
  for (int l = 0; l < 256; ++l) {
    // part 1: producers write ihbuf(l); wave4 polls h(l) (simple loop — r11)
    if (prod) {
#pragma unroll
      for (int t2 = 0; t2 < 2; ++t2) {
        float* b2 = ihb + ((gate * 2 + t2) * 8) * 64 + lane;
        if constexpr (LAYER == 0) {
#pragma unroll
          for (int r = 0; r < 4; ++r) {
            b2[r * 64] = phv[t2][r];
            b2[(4 + r) * 64] = (float)plv[t2][r];
          }
        } else {
#pragma unroll
          for (int r = 0; r < 4; ++r) {
            b2[r * 64] = ihA0[t2][r];
            b2[(4 + r) * 64] = ihA1[t2][r];
          }
        }
      }
    } else if (wv == 4 && l > 0) {
      const u64* pa = exchMy + (size_t)l * 1024 + g * 128 + 2 * lane;
      u64 v0 = ald(pa), v1 = ald(pa + 1);
      for (;;) {
        if (__all(((unsigned)v0 == (unsigned)l) && ((unsigned)v1 == (unsigned)l))) break;
        v0 = ald(pa);
        v1 = ald(pa + 1);
        if (++polls > POLL_MAX) break;
      }
      hw[2 * lane] = (unsigned)(v0 >> 32);
      hw[2 * lane + 1] = (unsigned)(v1 >> 32);
    }
    barrier_lds();  // A: ihbuf(l) + hw(l) ready (LDS-ordered; vmcnt in flight)
    // part 2: producers build ih(l+1); consumers do recurrent + spikes
    if (prod) {
      if (l < 255) {
        if constexpr (LAYER == 0) {
          issue_pl(l + 1);
        } else {
          consume_xw(l + 2);
          ih_mfma();
          if (l + 3 <= 256) issue_xw(l + 3);
        }
      }
    } else {
      floatx4 C0[2], C1[2];
#pragma unroll
      for (int t2 = 0; t2 < 2; ++t2) {
        const float* b2 = ihb + ((gate * 2 + t2) * 8) * 64 + lane;
#pragma unroll
        for (int r = 0; r < 4; ++r) {
          C0[t2][r] = b2[r * 64];
          C1[t2][r] = b2[(4 + r) * 64];
        }
      }
      if (l > 0) {
#pragma unroll
        for (int q = 0; q < 8; ++q) {
          unsigned mw = hw[q * 16 + m16];
          unsigned byt = (mw >> (8 * l16)) & 0xFFu;
          half8 af = *(const half8*)(lut + byt * 8);
          C0[0] = MFMA16(af, FH[0][q], C0[0]);
          C0[1] = MFMA16(af, FH[1][q], C0[1]);
          C1[0] = MFMA16(af, FL[0][q], C1[0]);
          C1[1] = MFMA16(af, FL[1][q], C1[1]);
        }
      }
      u64 bal[2][4];
#pragma unroll
      for (int r = 0; r < 4; ++r) {
        float p0 = C0[0][r] + bl[0] + C11 * C1[0][r];
        float p1 = C0[1][r] + bl[1] + C11 * C1[1][r];
        bal[0][r] = __ballot(p0 >= 0.0f);
        bal[1][r] = __ballot(p1 >= 0.0f);
      }
      if (lane == 0) {
#pragma unroll
        for (int t2 = 0; t2 < 2; ++t2)
#pragma unroll
          for (int r = 0; r < 4; ++r) spike[gate * 8 + t2 * 4 + r] = bal[t2][r];
      }
    }
    barrier_lds();  // B: spikes ready (LDS-ordered; vmcnt in flight)
    // part 3: bitwise update (all waves) + producer-side outputs
    {
      int idx = lane & 7;
      u64 iS = spike[idx], fS = spike[8 + idx];
      u64 gS = spike[16 + idx];
      cst = (fS & cst) | (iS & gS);  // c = min(f*c+i*g, 1) exactly
    }
    u64 hS = spike[24 + (lane & 7)] & cst;  // h = o*c
    if (wv == 0) {
      unsigned hu = gather16(hS);
      if (lane < 16)
        ast(exchMy + (size_t)(l + 1) * 1024 + g * 128 + kwg * 16 + lane,
            ((u64)hu << 32) | (unsigned)(l + 1));
    }
    if (LAYER == 1 && wv == 1) {
      unsigned hu = gather16(hS);
      if (lane < 16) {
        float* frow = dout + ((size_t)l * 128 + 16 * g + lane) * 256 + 32 * kwg;
#pragma unroll
        for (int c4 = 0; c4 < 8; ++c4) {
          floatx4 v;
#pragma unroll
          for (int j = 0; j < 4; ++j) v[j] = ((hu >> (c4 * 4 + j)) & 1) ? 1.0f : 0.0f;
          *(floatx4*)(frow + c4 * 4) = v;
        }
      }
    }
    if (l == 255 && wv == 2) {
      unsigned hu = gather16(hS);
      unsigned cu = gather16(cst);
      if (lane < 16) {
        float* shp = dout + 8388608 + LAYER * 32768 +
                     (size_t)(16 * g + lane) * 256 + 32 * kwg;
        float* scp = shp + 65536;
#pragma unroll
        for (int c4 = 0; c4 < 8; ++c4) {
          floatx4 vh, vc;
#pragma unroll
          for (int j = 0; j < 4; ++j) {
            vh[j] = ((hu >> (c4 * 4 + j)) & 1) ? 1.0f : 0.0f;
            vc[j] = ((cu >> (c4 * 4 + j)) & 1) ? 1.0f : 0.0f;
          }
          *(floatx4*)(shp + c4 * 4) = vh;
          *(floatx4*)(scp + c4 * 4) = vc;
        }
      }
    }
  }
}

__global__ __launch_bounds__(512, 2) void spike_scan(
    const float* __restrict__ wih1, const float* __restrict__ whh0,
    const float* __restrict__ whh1, const float* __restrict__ b0,
    const float* __restrict__ b1, float* __restrict__ dout) {
  __shared__ __align__(16) _Float16 lut[256 * 8];
  __shared__ __align__(16) float ihb[4 * 2 * 8 * 64];
  __shared__ unsigned hw[128];
  __shared__ u64 spike[32];

  int bi = blockIdx.x;  // 128 WGs: 64 per layer
  int g = bi & 7;
  int kwg = (bi >> 3) & 7;
  if ((bi >> 6) == 0)
    scan_body<0>(lut, ihb, hw, spike, (const float*)nullptr, whh0, b0, dout, g, kwg);
  else
    scan_body<1>(lut, ihb, hw, spike, wih1, whh1, b1, dout, g, kwg);
}

extern "C" void kernel_launch(void* const* d_in, const int* in_sizes, int n_in,
                              void* d_out, int out_size, void* d_ws, size_t ws_size,
                              hipStream_t stream) {
  (void)in_sizes; (void)n_in; (void)out_size; (void)d_ws; (void)ws_size;
  const float* x = (const float*)d_in[0];
  const float* wih0 = (const float*)d_in[1];
  const float* whh0 = (const float*)d_in[2];
  const float* b0 = (const float*)d_in[3];
  const float* wih1 = (const float*)d_in[4];
  const float* whh1 = (const float*)d_in[5];
  const float* b1 = (const float*)d_in[6];
  float* dout = (float*)d_out;

  presplit_k<<<4096, 256, 0, stream>>>(x);  // also zeroes the rings
  gemm0_k<<<512, 256, 0, stream>>>(wih0);
  spike_scan<<<128, 512, 0, stream>>>(wih1, whh0, whh1, b0, b1, dout);
}